// Round 13
// baseline (457.126 us; speedup 1.0000x reference)
//
#include <hip/hip_runtime.h>
#include <hip/hip_bf16.h>
#include <cstdint>
#include <cstddef>

// ---------- types ----------
typedef __attribute__((ext_vector_type(8))) short bfrag;   // 8 bf16 (4 VGPR) MFMA A/B frag
typedef __attribute__((ext_vector_type(4))) short short4v; // 8B packed bf16 quad
typedef __attribute__((ext_vector_type(4))) float facc;    // 4 f32 MFMA C/D frag

// HW RNE f32->bf16 (compiler pairs adjacent converts into v_cvt_pk_bf16_f32)
static __device__ __forceinline__ short f2bf(float f) {
  __hip_bfloat16 h = __float2bfloat16(f);
  return *reinterpret_cast<short*>(&h);
}
static __device__ __forceinline__ float bf2f(short s) {
  union { float f; unsigned int u; } c; c.u = ((unsigned int)(unsigned short)s) << 16;
  return c.f;
}

// async global->LDS, 16B per lane (dest = wave-uniform base + lane*16)
static __device__ __forceinline__ void gload16(const short* g, short* l) {
  __builtin_amdgcn_global_load_lds(
      (const __attribute__((address_space(1))) unsigned int*)(g),
      (__attribute__((address_space(3))) unsigned int*)(l), 16, 0, 0);
}

#define SL 0.18033688011112043f   // 0.125 * log2(e) — folded into q at gemm0 epilogue

// ---------- convert fp32 -> bf16 + fused gate ----------
__global__ __launch_bounds__(256) void cvt_rows_gate(
    const float* __restrict__ src, short* __restrict__ dst,
    const float* __restrict__ Wg, const float* __restrict__ bg,
    float* __restrict__ g) {
  const int t = threadIdx.x;
  size_t i = (size_t)blockIdx.x * 256 + t;
  const facc* s4 = (const facc*)src;
  facc v0 = s4[i * 2], v1 = s4[i * 2 + 1];
  bfrag o;
  o[0] = f2bf(v0[0]); o[1] = f2bf(v0[1]); o[2] = f2bf(v0[2]); o[3] = f2bf(v0[3]);
  o[4] = f2bf(v1[0]); o[5] = f2bf(v1[1]); o[6] = f2bf(v1[2]); o[7] = f2bf(v1[3]);
  *(bfrag*)(dst + i * 8) = o;
  const facc* wr = (const facc*)(Wg + (t & 127) * 8);
  facc w0 = wr[0], w1 = wr[1];
  float s = v0[0]*w0[0] + v0[1]*w0[1] + v0[2]*w0[2] + v0[3]*w0[3]
          + v1[0]*w1[0] + v1[1]*w1[1] + v1[2]*w1[2] + v1[3]*w1[3];
  #pragma unroll
  for (int mm = 1; mm < 64; mm <<= 1) s += __shfl_xor(s, mm);
  __shared__ float gsum[4];
  if ((t & 63) == 0) gsum[t >> 6] = s;
  __syncthreads();
  if ((t & 127) == 0) {
    int half = t >> 7;
    float tot = gsum[half * 2] + gsum[half * 2 + 1] + bg[0];
    g[blockIdx.x * 2 + half] = 1.f / (1.f + __expf(-tot));
  }
}

// ---------- convert + transpose both weights in one launch ----------
// bx<48: Wqkv (N=3072); else Wout (N=1024). dst[n*1024+k] = bf16(src[k*N+n])
__global__ __launch_bounds__(256) void cvt_T2(
    const float* __restrict__ s1, short* __restrict__ d1,
    const float* __restrict__ s2, short* __restrict__ d2) {
  __shared__ short tile[64][65];
  const int bx = blockIdx.x;
  const float* src; short* dst; int N; int n0;
  if (bx < 48) { src = s1; dst = d1; N = 3072; n0 = bx * 64; }
  else         { src = s2; dst = d2; N = 1024; n0 = (bx - 48) * 64; }
  int k0 = blockIdx.y * 64;
  int tx = threadIdx.x & 63, ty = threadIdx.x >> 6;
  #pragma unroll
  for (int i = ty; i < 64; i += 4)
    tile[i][tx] = f2bf(src[(size_t)(k0 + i) * N + n0 + tx]);
  __syncthreads();
  #pragma unroll
  for (int i = ty; i < 64; i += 4)
    dst[(size_t)(n0 + i) * 1024 + k0 + tx] = tile[tx][i];
}

// ---------- prep: V^T + compact strided K/V buffers ----------
__global__ __launch_bounds__(256) void prep_attn(
    const short* __restrict__ kb, const short* __restrict__ vb,
    short* __restrict__ vbt, short* __restrict__ vgt, short* __restrict__ kgs) {
  __shared__ short tile[64][65];
  const int t = threadIdx.x, tx = t & 63, ty = t >> 6;
  const int k0 = blockIdx.x * 64, bh = blockIdx.y;
  const size_t base = (size_t)bh * 262144;
  #pragma unroll
  for (int i = ty; i < 64; i += 4)
    tile[i][tx] = vb[base + (size_t)(k0 + i) * 64 + tx];
  __syncthreads();
  #pragma unroll
  for (int i = ty; i < 64; i += 4)
    vbt[base + (size_t)i * 4096 + k0 + tx] = tile[tx][i];
  if (t < 128) {
    int sk = t >> 6, d = t & 63;
    int gi = (k0 >> 5) + sk;
    vgt[(size_t)bh * 8192 + d * 128 + gi] = tile[sk * 32][d];
    kgs[(size_t)bh * 8192 + gi * 64 + d] = kb[base + (size_t)(k0 + sk * 32) * 64 + d];
  }
}

// ---------- bf16 GEMM: C[M,N] = A[M,K] @ Bt[N,K]^T ----------
template <int EPI>
__global__ __launch_bounds__(256) void gemm_bt(
    const short* __restrict__ A, const short* __restrict__ Bt,
    int M, int N, int K,
    short* __restrict__ q_out, short* __restrict__ k_out, short* __restrict__ v_out,
    float* __restrict__ out, const float* __restrict__ bias) {
  __shared__ short Ab[2][128 * 32];
  __shared__ short Bb[2][128 * 32];
  const int t = threadIdx.x;
  const int l = t & 63;
  const int tile_m = blockIdx.y * 128;
  const int tile_n = blockIdx.x * 128;
  const int w = t >> 6;
  const int wm = (w >> 1) * 64, wn = (w & 1) * 64;
  const int c0 = t, c1 = t + 256;

  facc acc[4][4];
  #pragma unroll
  for (int i = 0; i < 4; ++i)
    #pragma unroll
    for (int j = 0; j < 4; ++j) acc[i][j] = (facc){0.f, 0.f, 0.f, 0.f};

  const short* Abase = A + (size_t)tile_m * K;
  const short* Bbase = Bt + (size_t)tile_n * K;
  const size_t ga0 = (size_t)(c0 >> 2) * K + (c0 & 3) * 8;
  const size_t ga1 = (size_t)(c1 >> 2) * K + (c1 & 3) * 8;

  auto stage = [&](int k0, int buf) {
    gload16(Abase + ga0 + k0, &Ab[buf][c0 * 8]);
    gload16(Abase + ga1 + k0, &Ab[buf][c1 * 8]);
    gload16(Bbase + ga0 + k0, &Bb[buf][c0 * 8]);
    gload16(Bbase + ga1 + k0, &Bb[buf][c1 * 8]);
  };

  stage(0, 0);
  __syncthreads();
  int buf = 0;
  for (int k0 = 0; k0 < K; k0 += 32) {
    if (k0 + 32 < K) stage(k0 + 32, buf ^ 1);
    bfrag af[4], bf[4];
    #pragma unroll
    for (int i = 0; i < 4; ++i)
      af[i] = *(const bfrag*)&Ab[buf][(wm + i * 16 + (l & 15)) * 32 + ((l >> 4) << 3)];
    #pragma unroll
    for (int i = 0; i < 4; ++i)
      bf[i] = *(const bfrag*)&Bb[buf][(wn + i * 16 + (l & 15)) * 32 + ((l >> 4) << 3)];
    #pragma unroll
    for (int mt = 0; mt < 4; ++mt)
      #pragma unroll
      for (int nt = 0; nt < 4; ++nt)
        acc[mt][nt] = __builtin_amdgcn_mfma_f32_16x16x32_bf16(af[mt], bf[nt], acc[mt][nt], 0, 0, 0);
    __syncthreads();
    buf ^= 1;
  }

  #pragma unroll
  for (int mt = 0; mt < 4; ++mt)
    #pragma unroll
    for (int nt = 0; nt < 4; ++nt) {
      int col = tile_n + wn + nt * 16 + (l & 15);
      int row0 = tile_m + wm + mt * 16 + ((l >> 4) << 2);
      if (EPI == 0) {
        int which = col >> 10, rem = col & 1023, hh = rem >> 6, dd = rem & 63;
        short* dst = (which == 0) ? q_out : ((which == 1) ? k_out : v_out);
        float vsc = (which == 0) ? SL : 1.f;   // fold softmax scale+log2e into q
        #pragma unroll
        for (int r = 0; r < 4; ++r) {
          int m = row0 + r, b = m >> 12, s = m & 4095;
          dst[(((size_t)b * 16 + hh) * 4096 + s) * 64 + dd] = f2bf(acc[mt][nt][r] * vsc);
        }
      } else {
        float bv = bias[col];
        #pragma unroll
        for (int r = 0; r < 4; ++r)
          out[(size_t)(row0 + r) * N + col] = acc[mt][nt][r] + bv;
      }
    }
}

// ---------- fused attention ----------
// Round-13: NO K/V LDS staging — read MFMA fragments directly from global.
// With XCD-grouping, each XCD's K/V working set (4 bh x 1MB) ~= its 4MB L2,
// and all 8 waves of a block read the same tile (L1 catches reuse). This
// removes EVERY barrier from the main loop (round-12 showed the lockstep
// barrier convergence, not residency, was the stall: occupancy 2x'd, dur
// flat). P stays in per-wave LDS (same-wave DS ordering needs no barrier).
// Keeps: XCD-grouping, q pre-scaled by SL, ones-MFMA row sums, fixed-max
// softmax. LDS = Pb only (16KB). No occupancy cap (round-3 spill lesson).

__global__ __launch_bounds__(512) void attn_fused(
    const short* __restrict__ qg, const short* __restrict__ kg,
    const short* __restrict__ vbt, const short* __restrict__ vgt,
    const short* __restrict__ kgs,
    const float* __restrict__ gate, short* __restrict__ comb) {
  __shared__ short Pb[8][16 * 64];    // per-wave P [q][key]

  const int t = threadIdx.x, l = t & 63, w = t >> 6;   // w 0..7
  const int bid = blockIdx.x;
  // XCD-grouping: xcd = bid&7 owns bh = xcd*4 .. xcd*4+3, one bh at a time
  const int yy = bid >> 3;
  const int bh = (bid & 7) * 4 + (yy >> 5);
  const int qblk = yy & 31;
  const int q0 = qblk * 128;
  const int b = bh >> 4, h = bh & 15;
  const int lo = l & 15, hi = l >> 4, hi4 = (l >> 4) << 2;

  const int n = q0 >> 9;
  int kstart = n * 512 - 256; if (kstart < 0) kstart = 0;
  int kend = n * 512 + 768; if (kend > 4096) kend = 4096;
  const int nloc = (kend - kstart) >> 6;

  // Q fragments: wave owns 16 q rows at q0 + w*16
  const size_t qrow = (size_t)bh * 4096 + q0 + w * 16;
  bfrag qf[2];
  #pragma unroll
  for (int hf = 0; hf < 2; ++hf)
    qf[hf] = *(const bfrag*)(qg + (qrow + lo) * 64 + hf * 32 + hi * 8);

  // all-ones B fragment for row-sum MFMA (bf16 1.0 = 0x3F80)
  bfrag ones;
  #pragma unroll
  for (int i = 0; i < 8; ++i) ones[i] = (short)0x3F80;

  facc ls_l = (facc){0.f, 0.f, 0.f, 0.f};
  facc ls_g = (facc){0.f, 0.f, 0.f, 0.f};
  facc o_l[4], o_g[4];
  #pragma unroll
  for (int nt = 0; nt < 4; ++nt) {
    o_l[nt] = (facc){0.f, 0.f, 0.f, 0.f};
    o_g[nt] = (facc){0.f, 0.f, 0.f, 0.f};
  }

  const size_t kBaseL = (size_t)bh * 262144;      // kg / vbt
  const size_t sBase  = (size_t)bh * 8192;        // kgs / vgt
  const int gq = (lo & 7) ^ (lo >> 3);

  // kB: K rows base for tile ([key][64], row-major). vB: V^T tile base
  // ([d][vStride], key-col offset already applied).
  auto computeTile = [&](const short* kB, const short* vB, int vStride,
                         facc& ls, facc (&oacc)[4]) {
    bfrag kf[4][2], vf[4][2];
    #pragma unroll
    for (int kt = 0; kt < 4; ++kt)
      #pragma unroll
      for (int hf = 0; hf < 2; ++hf)
        kf[kt][hf] = *(const bfrag*)(kB + (size_t)(kt * 16 + lo) * 64 + hf * 32 + hi * 8);
    #pragma unroll
    for (int nt = 0; nt < 4; ++nt)
      #pragma unroll
      for (int hf = 0; hf < 2; ++hf)
        vf[nt][hf] = *(const bfrag*)(vB + (size_t)(nt * 16 + lo) * vStride + hf * 32 + hi * 8);
    short* Pw = &Pb[w][0];
    facc sA[4];
    #pragma unroll
    for (int kt = 0; kt < 4; ++kt) {
      facc z = (facc){0.f, 0.f, 0.f, 0.f};
      z = __builtin_amdgcn_mfma_f32_16x16x32_bf16(kf[kt][0], qf[0], z, 0, 0, 0);
      z = __builtin_amdgcn_mfma_f32_16x16x32_bf16(kf[kt][1], qf[1], z, 0, 0, 0);
      sA[kt] = z;
    }
    short4v pk[4];
    #pragma unroll
    for (int kt = 0; kt < 4; ++kt)
      #pragma unroll
      for (int rr = 0; rr < 4; ++rr)
        pk[kt][rr] = f2bf(exp2f(sA[kt][rr]));    // q pre-scaled by SL in gemm0
    #pragma unroll
    for (int kt = 0; kt < 4; ++kt)
      *(short4v*)&Pw[lo * 64 + ((kt * 16 + hi4) ^ (gq << 3))] = pk[kt];
    bfrag pf0 = *(const bfrag*)&Pw[lo * 64 + ((hi * 8) ^ (gq << 3))];
    bfrag pf1 = *(const bfrag*)&Pw[lo * 64 + ((32 + hi * 8) ^ (gq << 3))];
    // denominator on the matrix pipe: D[q][*] = sum_k P[q][k]
    ls = __builtin_amdgcn_mfma_f32_16x16x32_bf16(pf0, ones, ls, 0, 0, 0);
    ls = __builtin_amdgcn_mfma_f32_16x16x32_bf16(pf1, ones, ls, 0, 0, 0);
    #pragma unroll
    for (int nt = 0; nt < 4; ++nt) {
      facc oo = oacc[nt];
      oo = __builtin_amdgcn_mfma_f32_16x16x32_bf16(pf0, vf[nt][0], oo, 0, 0, 0);
      oo = __builtin_amdgcn_mfma_f32_16x16x32_bf16(pf1, vf[nt][1], oo, 0, 0, 0);
      oacc[nt] = oo;
    }
  };

  // ---- global phase (2 tiles of 64 strided keys) ----
  #pragma unroll
  for (int itg = 0; itg < 2; ++itg)
    computeTile(kgs + sBase + (size_t)itg * 64 * 64,
                vgt + sBase + itg * 64, 128, ls_g, o_g);

  // normalize + pack o_g to bf16 (frees o_g/ls_g registers for local phase)
  unsigned ogp[8];
  {
    float inv[4];
    #pragma unroll
    for (int rr = 0; rr < 4; ++rr) inv[rr] = 1.f / ls_g[rr];
    #pragma unroll
    for (int nt = 0; nt < 4; ++nt)
      #pragma unroll
      for (int rp = 0; rp < 2; ++rp) {
        unsigned a = (unsigned short)f2bf(o_g[nt][rp * 2] * inv[rp * 2]);
        unsigned bq = (unsigned short)f2bf(o_g[nt][rp * 2 + 1] * inv[rp * 2 + 1]);
        ogp[nt * 2 + rp] = a | (bq << 16);
      }
  }

  // ---- local phase (no barriers: waves fully independent) ----
  for (int itl = 0; itl < nloc; ++itl) {
    const int col = kstart + itl * 64;
    computeTile(kg + kBaseL + (size_t)col * 64,
                vbt + kBaseL + col, 4096, ls_l, o_l);
  }

  // ---- epilogue: gate-combine (denominators lane-local, no shuffles) ----
  #pragma unroll
  for (int rr = 0; rr < 4; ++rr) {
    float invl = 1.f / ls_l[rr];
    int q = q0 + w * 16 + hi4 + rr;
    float gg = gate[b * 4096 + q];
    size_t obase = ((size_t)b * 4096 + q) * 1024 + h * 64;
    #pragma unroll
    for (int nt = 0; nt < 4; ++nt) {
      unsigned pw = ogp[nt * 2 + (rr >> 1)];
      float og = bf2f((short)((rr & 1) ? (pw >> 16) : (pw & 0xffff)));
      float val = gg * o_l[nt][rr] * invl + (1.f - gg) * og;
      comb[obase + nt * 16 + lo] = f2bf(val);
    }
  }
}

// ---------- launch ----------
extern "C" void kernel_launch(void* const* d_in, const int* in_sizes, int n_in,
                              void* d_out, int out_size, void* d_ws, size_t ws_size,
                              hipStream_t stream) {
  const float* x    = (const float*)d_in[0];
  const float* Wqkv = (const float*)d_in[1];
  const float* Wg   = (const float*)d_in[2];
  const float* bg   = (const float*)d_in[3];
  const float* Wout = (const float*)d_in[4];
  const float* bout = (const float*)d_in[5];
  float* out = (float*)d_out;

  char* p = (char*)d_ws;
  short* xbf   = (short*)p; p += (size_t)8192 * 1024 * 2;   // reused as comb
  short* WqkvT = (short*)p; p += (size_t)3072 * 1024 * 2;   // dead after gemm0
  short* WoutT = (short*)p; p += (size_t)1024 * 1024 * 2;
  short* qb    = (short*)p; p += (size_t)32 * 4096 * 64 * 2;
  short* kb    = (short*)p; p += (size_t)32 * 4096 * 64 * 2;
  short* vb    = (short*)p; p += (size_t)32 * 4096 * 64 * 2;
  float* g     = (float*)p; p += (size_t)8192 * 4;
  short* vbt   = (short*)p; p += (size_t)32 * 64 * 4096 * 2;
  short* comb  = xbf;                      // alias: xbf dead after gemm<0>
  short* vgt   = WqkvT;                    // alias: WqkvT dead after gemm<0>
  short* kgs   = WqkvT + (size_t)32 * 64 * 128;

  cvt_rows_gate<<<4096, 256, 0, stream>>>(x, xbf, Wg, bg, g);
  cvt_T2<<<dim3(64, 16), 256, 0, stream>>>(Wqkv, WqkvT, Wout, WoutT);
  gemm_bt<0><<<dim3(24, 64), 256, 0, stream>>>(xbf, WqkvT, 8192, 3072, 1024,
                                               qb, kb, vb, nullptr, nullptr);
  prep_attn<<<dim3(64, 32), 256, 0, stream>>>(kb, vb, vbt, vgt, kgs);
  attn_fused<<<1024, 512, 0, stream>>>(qb, kb, vbt, vgt, kgs, g, comb);
  gemm_bt<1><<<dim3(8, 64), 256, 0, stream>>>(comb, WoutT, 8192, 1024, 1024,
                                              nullptr, nullptr, nullptr, out, bout);
}

// Round 14
// 268.611 us; speedup vs baseline: 1.7018x; 1.7018x over previous
//
#include <hip/hip_runtime.h>
#include <hip/hip_bf16.h>
#include <cstdint>
#include <cstddef>

// ---------- types ----------
typedef __attribute__((ext_vector_type(8))) short bfrag;   // 8 bf16 (4 VGPR) MFMA A/B frag
typedef __attribute__((ext_vector_type(4))) short short4v; // 8B packed bf16 quad
typedef __attribute__((ext_vector_type(4))) float facc;    // 4 f32 MFMA C/D frag

// HW RNE f32->bf16 (compiler pairs adjacent converts into v_cvt_pk_bf16_f32)
static __device__ __forceinline__ short f2bf(float f) {
  __hip_bfloat16 h = __float2bfloat16(f);
  return *reinterpret_cast<short*>(&h);
}
static __device__ __forceinline__ float bf2f(short s) {
  union { float f; unsigned int u; } c; c.u = ((unsigned int)(unsigned short)s) << 16;
  return c.f;
}

// async global->LDS, 16B per lane (dest = wave-uniform base + lane*16)
static __device__ __forceinline__ void gload16(const short* g, short* l) {
  __builtin_amdgcn_global_load_lds(
      (const __attribute__((address_space(1))) unsigned int*)(g),
      (__attribute__((address_space(3))) unsigned int*)(l), 16, 0, 0);
}

#define SL 0.18033688011112043f   // 0.125 * log2(e) — folded into q at gemm0 epilogue

// ---------- convert fp32 -> bf16 + fused gate ----------
__global__ __launch_bounds__(256) void cvt_rows_gate(
    const float* __restrict__ src, short* __restrict__ dst,
    const float* __restrict__ Wg, const float* __restrict__ bg,
    float* __restrict__ g) {
  const int t = threadIdx.x;
  size_t i = (size_t)blockIdx.x * 256 + t;
  const facc* s4 = (const facc*)src;
  facc v0 = s4[i * 2], v1 = s4[i * 2 + 1];
  bfrag o;
  o[0] = f2bf(v0[0]); o[1] = f2bf(v0[1]); o[2] = f2bf(v0[2]); o[3] = f2bf(v0[3]);
  o[4] = f2bf(v1[0]); o[5] = f2bf(v1[1]); o[6] = f2bf(v1[2]); o[7] = f2bf(v1[3]);
  *(bfrag*)(dst + i * 8) = o;
  const facc* wr = (const facc*)(Wg + (t & 127) * 8);
  facc w0 = wr[0], w1 = wr[1];
  float s = v0[0]*w0[0] + v0[1]*w0[1] + v0[2]*w0[2] + v0[3]*w0[3]
          + v1[0]*w1[0] + v1[1]*w1[1] + v1[2]*w1[2] + v1[3]*w1[3];
  #pragma unroll
  for (int mm = 1; mm < 64; mm <<= 1) s += __shfl_xor(s, mm);
  __shared__ float gsum[4];
  if ((t & 63) == 0) gsum[t >> 6] = s;
  __syncthreads();
  if ((t & 127) == 0) {
    int half = t >> 7;
    float tot = gsum[half * 2] + gsum[half * 2 + 1] + bg[0];
    g[blockIdx.x * 2 + half] = 1.f / (1.f + __expf(-tot));
  }
}

// ---------- convert + transpose both weights in one launch ----------
// bx<48: Wqkv (N=3072); else Wout (N=1024). dst[n*1024+k] = bf16(src[k*N+n])
__global__ __launch_bounds__(256) void cvt_T2(
    const float* __restrict__ s1, short* __restrict__ d1,
    const float* __restrict__ s2, short* __restrict__ d2) {
  __shared__ short tile[64][65];
  const int bx = blockIdx.x;
  const float* src; short* dst; int N; int n0;
  if (bx < 48) { src = s1; dst = d1; N = 3072; n0 = bx * 64; }
  else         { src = s2; dst = d2; N = 1024; n0 = (bx - 48) * 64; }
  int k0 = blockIdx.y * 64;
  int tx = threadIdx.x & 63, ty = threadIdx.x >> 6;
  #pragma unroll
  for (int i = ty; i < 64; i += 4)
    tile[i][tx] = f2bf(src[(size_t)(k0 + i) * N + n0 + tx]);
  __syncthreads();
  #pragma unroll
  for (int i = ty; i < 64; i += 4)
    dst[(size_t)(n0 + i) * 1024 + k0 + tx] = tile[tx][i];
}

// ---------- prep: V^T + compact strided K/V buffers ----------
__global__ __launch_bounds__(256) void prep_attn(
    const short* __restrict__ kb, const short* __restrict__ vb,
    short* __restrict__ vbt, short* __restrict__ vgt, short* __restrict__ kgs) {
  __shared__ short tile[64][65];
  const int t = threadIdx.x, tx = t & 63, ty = t >> 6;
  const int k0 = blockIdx.x * 64, bh = blockIdx.y;
  const size_t base = (size_t)bh * 262144;
  #pragma unroll
  for (int i = ty; i < 64; i += 4)
    tile[i][tx] = vb[base + (size_t)(k0 + i) * 64 + tx];
  __syncthreads();
  #pragma unroll
  for (int i = ty; i < 64; i += 4)
    vbt[base + (size_t)i * 4096 + k0 + tx] = tile[tx][i];
  if (t < 128) {
    int sk = t >> 6, d = t & 63;
    int gi = (k0 >> 5) + sk;
    vgt[(size_t)bh * 8192 + d * 128 + gi] = tile[sk * 32][d];
    kgs[(size_t)bh * 8192 + gi * 64 + d] = kb[base + (size_t)(k0 + sk * 32) * 64 + d];
  }
}

// ---------- bf16 GEMM: C[M,N] = A[M,K] @ Bt[N,K]^T ----------
template <int EPI>
__global__ __launch_bounds__(256) void gemm_bt(
    const short* __restrict__ A, const short* __restrict__ Bt,
    int M, int N, int K,
    short* __restrict__ q_out, short* __restrict__ k_out, short* __restrict__ v_out,
    float* __restrict__ out, const float* __restrict__ bias) {
  __shared__ short Ab[2][128 * 32];
  __shared__ short Bb[2][128 * 32];
  const int t = threadIdx.x;
  const int l = t & 63;
  const int tile_m = blockIdx.y * 128;
  const int tile_n = blockIdx.x * 128;
  const int w = t >> 6;
  const int wm = (w >> 1) * 64, wn = (w & 1) * 64;
  const int c0 = t, c1 = t + 256;

  facc acc[4][4];
  #pragma unroll
  for (int i = 0; i < 4; ++i)
    #pragma unroll
    for (int j = 0; j < 4; ++j) acc[i][j] = (facc){0.f, 0.f, 0.f, 0.f};

  const short* Abase = A + (size_t)tile_m * K;
  const short* Bbase = Bt + (size_t)tile_n * K;
  const size_t ga0 = (size_t)(c0 >> 2) * K + (c0 & 3) * 8;
  const size_t ga1 = (size_t)(c1 >> 2) * K + (c1 & 3) * 8;

  auto stage = [&](int k0, int buf) {
    gload16(Abase + ga0 + k0, &Ab[buf][c0 * 8]);
    gload16(Abase + ga1 + k0, &Ab[buf][c1 * 8]);
    gload16(Bbase + ga0 + k0, &Bb[buf][c0 * 8]);
    gload16(Bbase + ga1 + k0, &Bb[buf][c1 * 8]);
  };

  stage(0, 0);
  __syncthreads();
  int buf = 0;
  for (int k0 = 0; k0 < K; k0 += 32) {
    if (k0 + 32 < K) stage(k0 + 32, buf ^ 1);
    bfrag af[4], bf[4];
    #pragma unroll
    for (int i = 0; i < 4; ++i)
      af[i] = *(const bfrag*)&Ab[buf][(wm + i * 16 + (l & 15)) * 32 + ((l >> 4) << 3)];
    #pragma unroll
    for (int i = 0; i < 4; ++i)
      bf[i] = *(const bfrag*)&Bb[buf][(wn + i * 16 + (l & 15)) * 32 + ((l >> 4) << 3)];
    #pragma unroll
    for (int mt = 0; mt < 4; ++mt)
      #pragma unroll
      for (int nt = 0; nt < 4; ++nt)
        acc[mt][nt] = __builtin_amdgcn_mfma_f32_16x16x32_bf16(af[mt], bf[nt], acc[mt][nt], 0, 0, 0);
    __syncthreads();
    buf ^= 1;
  }

  #pragma unroll
  for (int mt = 0; mt < 4; ++mt)
    #pragma unroll
    for (int nt = 0; nt < 4; ++nt) {
      int col = tile_n + wn + nt * 16 + (l & 15);
      int row0 = tile_m + wm + mt * 16 + ((l >> 4) << 2);
      if (EPI == 0) {
        int which = col >> 10, rem = col & 1023, hh = rem >> 6, dd = rem & 63;
        short* dst = (which == 0) ? q_out : ((which == 1) ? k_out : v_out);
        float vsc = (which == 0) ? SL : 1.f;   // fold softmax scale+log2e into q
        #pragma unroll
        for (int r = 0; r < 4; ++r) {
          int m = row0 + r, b = m >> 12, s = m & 4095;
          dst[(((size_t)b * 16 + hh) * 4096 + s) * 64 + dd] = f2bf(acc[mt][nt][r] * vsc);
        }
      } else {
        float bv = bias[col];
        #pragma unroll
        for (int r = 0; r < 4; ++r)
          out[(size_t)(row0 + r) * N + col] = acc[mt][nt][r] + bv;
      }
    }
}

// ---------- fused attention ----------
// Round-14: revert to round-12 staged structure (round-13 direct-global was
// latency-bound: 268us, MfmaUtil 6% — staging's bulk transactions + tile
// overlap were essential). Surgical changes only:
//  (a) exp2f -> __builtin_amdgcn_exp2f: raw v_exp_f32, no libcall range
//      scaffolding (round-12's 54% VALUBusy didn't match the op audit;
//      the exp2f lowering is the hidden VALU hog). Args bounded |x|<~25.
//  (b) staging addresses: per-thread base pointers + small offsets instead
//      of rebuilding 64-bit addresses every tile.
// Keeps: XCD-grouping, gload_lds dbuf, q pre-scaled by SL, ones-MFMA row
// sums, single Pb per wave, fixed-max softmax, 8 waves x 16 q.

__global__ __launch_bounds__(512) void attn_fused(
    const short* __restrict__ qg, const short* __restrict__ kg,
    const short* __restrict__ vbt, const short* __restrict__ vgt,
    const short* __restrict__ kgs,
    const float* __restrict__ gate, short* __restrict__ comb) {
  __shared__ short Kt[2][64 * 64];    // [key][d], rows 128B, slot-swizzled
  __shared__ short Vt[2][64 * 64];    // [d][key], rows 128B, slot-swizzled
  __shared__ short Pb[8][16 * 64];    // per-wave P [q][key]

  const int t = threadIdx.x, l = t & 63, w = t >> 6;   // w 0..7
  const int bid = blockIdx.x;
  // XCD-grouping: xcd = bid&7 owns bh = xcd*4 .. xcd*4+3, one bh at a time
  const int yy = bid >> 3;
  const int bh = (bid & 7) * 4 + (yy >> 5);
  const int qblk = yy & 31;
  const int q0 = qblk * 128;
  const int b = bh >> 4, h = bh & 15;
  const int lo = l & 15, hi = l >> 4, hi4 = (l >> 4) << 2;

  const int n = q0 >> 9;
  int kstart = n * 512 - 256; if (kstart < 0) kstart = 0;
  int kend = n * 512 + 768; if (kend > 4096) kend = 4096;
  const int nloc = (kend - kstart) >> 6;

  // Q fragments: wave owns 16 q rows at q0 + w*16
  const size_t qrow = (size_t)bh * 4096 + q0 + w * 16;
  bfrag qf[2];
  #pragma unroll
  for (int hf = 0; hf < 2; ++hf)
    qf[hf] = *(const bfrag*)(qg + (qrow + lo) * 64 + hf * 32 + hi * 8);

  // all-ones B fragment for row-sum MFMA (bf16 1.0 = 0x3F80)
  bfrag ones;
  #pragma unroll
  for (int i = 0; i < 8; ++i) ones[i] = (short)0x3F80;

  facc ls_l = (facc){0.f, 0.f, 0.f, 0.f};
  facc ls_g = (facc){0.f, 0.f, 0.f, 0.f};
  facc o_l[4], o_g[4];
  #pragma unroll
  for (int nt = 0; nt < 4; ++nt) {
    o_l[nt] = (facc){0.f, 0.f, 0.f, 0.f};
    o_g[nt] = (facc){0.f, 0.f, 0.f, 0.f};
  }

  // staging chunk: c = t (0..511) -> row r = c>>3 (key for K, d for V), slot s
  const int c = t, r = c >> 3;
  const int sl = (c & 7) ^ ((r & 7) ^ (r >> 3));

  const size_t kBaseL = (size_t)bh * 262144;      // kg / vbt
  const size_t sBase  = (size_t)bh * 8192;        // kgs / vgt

  // precomputed per-thread staging source pointers (base + small offset/iter)
  const short* kP  = kg  + kBaseL + (size_t)(kstart + r) * 64 + sl * 8;
  const short* vP  = vbt + kBaseL + (size_t)r * 4096 + kstart + sl * 8;
  const short* kgP = kgs + sBase + (size_t)r * 64 + sl * 8;
  const short* vgP = vgt + sBase + (size_t)r * 128 + sl * 8;

  auto stageLoc = [&](int itl, int buf) {
    gload16(kP + (size_t)itl * 4096, &Kt[buf][c * 8]);   // 64 rows * 64 elems
    gload16(vP + itl * 64, &Vt[buf][c * 8]);
  };
  auto stageGlb = [&](int itg, int buf) {
    gload16(kgP + (size_t)itg * 4096, &Kt[buf][c * 8]);
    gload16(vgP + itg * 64, &Vt[buf][c * 8]);
  };

  const int gq = (lo & 7) ^ (lo >> 3);
  auto computeTile = [&](int buf, facc& ls, facc (&oacc)[4]) {
    bfrag kf[4][2];
    #pragma unroll
    for (int kt = 0; kt < 4; ++kt) {
      int key = kt * 16 + lo; int gk2 = (key & 7) ^ (key >> 3);
      const short* Kr = &Kt[buf][key * 64];
      kf[kt][0] = *(const bfrag*)&Kr[(hi * 8) ^ (gk2 << 3)];
      kf[kt][1] = *(const bfrag*)&Kr[(32 + hi * 8) ^ (gk2 << 3)];
    }
    bfrag vf[4][2];
    #pragma unroll
    for (int nt = 0; nt < 4; ++nt) {
      int d = nt * 16 + lo; int gd = (d & 7) ^ (d >> 3);
      const short* Vr = &Vt[buf][d * 64];
      vf[nt][0] = *(const bfrag*)&Vr[(hi * 8) ^ (gd << 3)];
      vf[nt][1] = *(const bfrag*)&Vr[(32 + hi * 8) ^ (gd << 3)];
    }
    short* Pw = &Pb[w][0];
    facc sA[4];
    #pragma unroll
    for (int kt = 0; kt < 4; ++kt) {
      facc z = (facc){0.f, 0.f, 0.f, 0.f};
      z = __builtin_amdgcn_mfma_f32_16x16x32_bf16(kf[kt][0], qf[0], z, 0, 0, 0);
      z = __builtin_amdgcn_mfma_f32_16x16x32_bf16(kf[kt][1], qf[1], z, 0, 0, 0);
      sA[kt] = z;
    }
    short4v pk[4];
    #pragma unroll
    for (int kt = 0; kt < 4; ++kt)
      #pragma unroll
      for (int rr = 0; rr < 4; ++rr)
        pk[kt][rr] = f2bf(__builtin_amdgcn_exp2f(sA[kt][rr]));  // raw v_exp_f32
    #pragma unroll
    for (int kt = 0; kt < 4; ++kt)
      *(short4v*)&Pw[lo * 64 + ((kt * 16 + hi4) ^ (gq << 3))] = pk[kt];
    bfrag pf0 = *(const bfrag*)&Pw[lo * 64 + ((hi * 8) ^ (gq << 3))];
    bfrag pf1 = *(const bfrag*)&Pw[lo * 64 + ((32 + hi * 8) ^ (gq << 3))];
    // denominator on the matrix pipe: D[q][*] = sum_k P[q][k]
    ls = __builtin_amdgcn_mfma_f32_16x16x32_bf16(pf0, ones, ls, 0, 0, 0);
    ls = __builtin_amdgcn_mfma_f32_16x16x32_bf16(pf1, ones, ls, 0, 0, 0);
    #pragma unroll
    for (int nt = 0; nt < 4; ++nt) {
      facc oo = oacc[nt];
      oo = __builtin_amdgcn_mfma_f32_16x16x32_bf16(pf0, vf[nt][0], oo, 0, 0, 0);
      oo = __builtin_amdgcn_mfma_f32_16x16x32_bf16(pf1, vf[nt][1], oo, 0, 0, 0);
      oacc[nt] = oo;
    }
  };

  // ---- global phase (2 tiles of 64 strided keys) ----
  stageGlb(0, 0);
  __syncthreads();                 // tile g0 ready
  stageGlb(1, 1);
  computeTile(0, ls_g, o_g);
  __syncthreads();                 // g1 ready; all waves done with buf 0
  stageLoc(0, 0);                  // local tile 0 loads overlap g1 compute
  computeTile(1, ls_g, o_g);

  // normalize + pack o_g to bf16 (frees o_g/ls_g registers for local phase)
  unsigned ogp[8];
  {
    float inv[4];
    #pragma unroll
    for (int rr = 0; rr < 4; ++rr) inv[rr] = 1.f / ls_g[rr];
    #pragma unroll
    for (int nt = 0; nt < 4; ++nt)
      #pragma unroll
      for (int rp = 0; rp < 2; ++rp) {
        unsigned a = (unsigned short)f2bf(o_g[nt][rp * 2] * inv[rp * 2]);
        unsigned bq = (unsigned short)f2bf(o_g[nt][rp * 2 + 1] * inv[rp * 2 + 1]);
        ogp[nt * 2 + rp] = a | (bq << 16);
      }
  }
  __syncthreads();                 // loc0 ready; all waves done with buf 1

  // ---- local phase ----
  int buf = 0;
  for (int itl = 0; itl < nloc; ++itl) {
    if (itl + 1 < nloc) stageLoc(itl + 1, buf ^ 1);
    computeTile(buf, ls_l, o_l);
    __syncthreads();               // next tile ready + cur fully consumed
    buf ^= 1;
  }

  // ---- epilogue: gate-combine (denominators lane-local, no shuffles) ----
  #pragma unroll
  for (int rr = 0; rr < 4; ++rr) {
    float invl = 1.f / ls_l[rr];
    int q = q0 + w * 16 + hi4 + rr;
    float gg = gate[b * 4096 + q];
    size_t obase = ((size_t)b * 4096 + q) * 1024 + h * 64;
    #pragma unroll
    for (int nt = 0; nt < 4; ++nt) {
      unsigned pw = ogp[nt * 2 + (rr >> 1)];
      float og = bf2f((short)((rr & 1) ? (pw >> 16) : (pw & 0xffff)));
      float val = gg * o_l[nt][rr] * invl + (1.f - gg) * og;
      comb[obase + nt * 16 + lo] = f2bf(val);
    }
  }
}

// ---------- launch ----------
extern "C" void kernel_launch(void* const* d_in, const int* in_sizes, int n_in,
                              void* d_out, int out_size, void* d_ws, size_t ws_size,
                              hipStream_t stream) {
  const float* x    = (const float*)d_in[0];
  const float* Wqkv = (const float*)d_in[1];
  const float* Wg   = (const float*)d_in[2];
  const float* bg   = (const float*)d_in[3];
  const float* Wout = (const float*)d_in[4];
  const float* bout = (const float*)d_in[5];
  float* out = (float*)d_out;

  char* p = (char*)d_ws;
  short* xbf   = (short*)p; p += (size_t)8192 * 1024 * 2;   // reused as comb
  short* WqkvT = (short*)p; p += (size_t)3072 * 1024 * 2;   // dead after gemm0
  short* WoutT = (short*)p; p += (size_t)1024 * 1024 * 2;
  short* qb    = (short*)p; p += (size_t)32 * 4096 * 64 * 2;
  short* kb    = (short*)p; p += (size_t)32 * 4096 * 64 * 2;
  short* vb    = (short*)p; p += (size_t)32 * 4096 * 64 * 2;
  float* g     = (float*)p; p += (size_t)8192 * 4;
  short* vbt   = (short*)p; p += (size_t)32 * 64 * 4096 * 2;
  short* comb  = xbf;                      // alias: xbf dead after gemm<0>
  short* vgt   = WqkvT;                    // alias: WqkvT dead after gemm<0>
  short* kgs   = WqkvT + (size_t)32 * 64 * 128;

  cvt_rows_gate<<<4096, 256, 0, stream>>>(x, xbf, Wg, bg, g);
  cvt_T2<<<dim3(64, 16), 256, 0, stream>>>(Wqkv, WqkvT, Wout, WoutT);
  gemm_bt<0><<<dim3(24, 64), 256, 0, stream>>>(xbf, WqkvT, 8192, 3072, 1024,
                                               qb, kb, vb, nullptr, nullptr);
  prep_attn<<<dim3(64, 32), 256, 0, stream>>>(kb, vb, vbt, vgt, kgs);
  attn_fused<<<1024, 512, 0, stream>>>(qb, kb, vbt, vgt, kgs, g, comb);
  gemm_bt<1><<<dim3(8, 64), 256, 0, stream>>>(comb, WoutT, 8192, 1024, 1024,
                                              nullptr, nullptr, nullptr, out, bout);
}